// Round 1
// baseline (1437.476 us; speedup 1.0000x reference)
//
#include <hip/hip_runtime.h>
#include <hip/hip_bf16.h>
#include <float.h>
#include <math.h>

// Problem constants
#define NB      4
#define QN      128
#define HID     512
#define NMEM    20000
#define NCHUNK  625
#define CHUNK   32
#define HEADS   8
#define DHEAD   64
#define TOPKK   8
#define NKV     1024   // 2*HEADS*DHEAD
#define LOGIT_SCALE 0.044194173824159216f  // 512^-0.5

typedef __attribute__((ext_vector_type(8))) short bf16x8;
typedef __attribute__((ext_vector_type(4))) float f32x4;

__device__ __forceinline__ short f2bf(float f){
  __hip_bfloat16 h = __float2bfloat16(f);
  return *reinterpret_cast<short*>(&h);
}
__device__ __forceinline__ float bf2f(unsigned short s){
  __hip_bfloat16 h;
  *reinterpret_cast<unsigned short*>(&h) = s;
  return __bfloat162float(h);
}
__device__ __forceinline__ bool mask_at(const void* m, int flag, long i){
  return flag ? (((const unsigned char*)m)[i] != 0)
              : (((const int*)m)[i] != 0);
}

// ---------------- misc: pos table + mask-layout flag ----------------
__global__ __launch_bounds__(512) void misc_kernel(float* __restrict__ pos,
                                                   int* __restrict__ flagp,
                                                   const void* __restrict__ mask){
  int c = blockIdx.x;      // 0..31
  int d = threadIdx.x;     // 0..511
  int j = (d < 256) ? d : d - 256;
  // inv_freq = 10000^(-(2j)/512)
  float invf = expf(-((2.0f * (float)j) / 512.0f) * 9.2103403719761836f);
  float arg = (float)(31 - c) * invf;
  pos[c * 512 + d] = (d < 256) ? sinf(arg) : cosf(arg);
  if (c == 0 && d == 0){
    // all-true bool mask: byte layout -> byte1==1 ; int32 layout -> byte1==0
    const unsigned char* mb = (const unsigned char*)mask;
    *flagp = (mb[1] != 0) ? 1 : 0;
  }
}

// ---------------- fold out_w @ fc2_w ----------------
__global__ __launch_bounds__(512) void fold_kernel(const float* __restrict__ out_w,
                                                   const float* __restrict__ out_b,
                                                   const float* __restrict__ fc2_w,
                                                   const float* __restrict__ fc2_b,
                                                   float* __restrict__ Wf,
                                                   float* __restrict__ bf){
  int j = blockIdx.x;   // 0..4
  int d = threadIdx.x;  // 0..511
  float s = 0.f;
  for (int k = 0; k < 512; ++k) s += out_w[d * 512 + k] * fc2_w[k * 5 + j];
  Wf[d * 5 + j] = s;
  if (d == 0){
    float sb = 0.f;
    for (int k = 0; k < 512; ++k) sb += out_b[k] * fc2_w[k * 5 + j];
    bf[j] = sb + fc2_b[j];
  }
}

// ---------------- chunk summarize ----------------
__global__ __launch_bounds__(512) void sum_kernel(const float* __restrict__ memories,
                                                  const void* __restrict__ mask,
                                                  const int* __restrict__ flagp,
                                                  float* __restrict__ summ,
                                                  float* __restrict__ chunkden){
  int blk = blockIdx.x;              // 0..2499 = b*625+n
  int b = blk / NCHUNK, n = blk % NCHUNK;
  int t = threadIdx.x;
  int flag = *flagp;
  long mbase = (long)b * NMEM + (long)n * CHUNK;
  float den = 0.f;
  for (int c = 0; c < CHUNK; ++c) den += mask_at(mask, flag, mbase + c) ? 1.f : 0.f;
  const float* rowb = memories + mbase * HID;
  float s = 0.f;
  for (int c = 0; c < CHUNK; ++c){
    if (mask_at(mask, flag, mbase + c)) s += rowb[(long)c * HID + t];
  }
  summ[(long)blk * HID + t] = s / (den + 1e-5f);
  if (t == 0) chunkden[blk] = den;
}

// ---------------- generic f32 GEMM: C[MxN] = A[MxK] @ B[KxN] (*scale, +bias) ----------------
__global__ __launch_bounds__(256) void gemm_f32(const float* __restrict__ A,
                                                const float* __restrict__ B,
                                                const float* __restrict__ bias,
                                                float* __restrict__ C,
                                                int M, int N, int K, float scale){
  __shared__ float As[16][65];
  __shared__ float Bs[16][65];
  int tx = threadIdx.x & 15, ty = threadIdx.x >> 4;
  int m0 = blockIdx.x * 64, n0 = blockIdx.y * 64;
  float acc[4][4] = {};
  for (int k0 = 0; k0 < K; k0 += 16){
    for (int idx = threadIdx.x; idx < 64 * 16; idx += 256){
      int r = idx >> 4, c = idx & 15;
      int gm = m0 + r;
      As[c][r] = (gm < M) ? A[(long)gm * K + k0 + c] : 0.f;
    }
    for (int idx = threadIdx.x; idx < 16 * 64; idx += 256){
      int r = idx >> 6, c = idx & 63;
      int gn = n0 + c;
      Bs[r][c] = (gn < N) ? B[(long)(k0 + r) * N + gn] : 0.f;
    }
    __syncthreads();
#pragma unroll
    for (int kk = 0; kk < 16; ++kk){
      float a[4], bb[4];
#pragma unroll
      for (int u = 0; u < 4; ++u){ a[u] = As[kk][ty * 4 + u]; bb[u] = Bs[kk][tx * 4 + u]; }
#pragma unroll
      for (int i = 0; i < 4; ++i)
#pragma unroll
        for (int jj = 0; jj < 4; ++jj) acc[i][jj] += a[i] * bb[jj];
    }
    __syncthreads();
  }
  for (int i = 0; i < 4; ++i){
    int gm = m0 + ty * 4 + i; if (gm >= M) continue;
    for (int jj = 0; jj < 4; ++jj){
      int gn = n0 + tx * 4 + jj; if (gn >= N) continue;
      float v = acc[i][jj] * scale;
      if (bias) v += bias[gn];
      C[(long)gm * N + gn] = v;
    }
  }
}

// ---------------- logits: per batch sq(128xK) @ sk(625xK)^T * scale, mask-any ----------------
__global__ __launch_bounds__(256) void logits_kernel(const float* __restrict__ sq,
                                                     const float* __restrict__ sk,
                                                     const float* __restrict__ chunkden,
                                                     float* __restrict__ logits){
  int b = blockIdx.z;
  int n0 = blockIdx.x * 64, i0 = blockIdx.y * 64;
  const float* A = sq + (long)b * QN * HID;
  const float* B = sk + (long)b * NCHUNK * HID;
  __shared__ float As[16][65];
  __shared__ float Bs[16][65];
  int tx = threadIdx.x & 15, ty = threadIdx.x >> 4;
  float acc[4][4] = {};
  for (int k0 = 0; k0 < HID; k0 += 16){
    for (int idx = threadIdx.x; idx < 64 * 16; idx += 256){
      int r = idx >> 4, c = idx & 15;
      As[c][r] = A[(long)(i0 + r) * HID + k0 + c];
    }
    for (int idx = threadIdx.x; idx < 64 * 16; idx += 256){
      int r = idx >> 4, c = idx & 15;
      int gn = n0 + r;
      Bs[c][r] = (gn < NCHUNK) ? B[(long)gn * HID + k0 + c] : 0.f;
    }
    __syncthreads();
#pragma unroll
    for (int kk = 0; kk < 16; ++kk){
      float a[4], bb[4];
#pragma unroll
      for (int u = 0; u < 4; ++u){ a[u] = As[kk][ty * 4 + u]; bb[u] = Bs[kk][tx * 4 + u]; }
#pragma unroll
      for (int i = 0; i < 4; ++i)
#pragma unroll
        for (int jj = 0; jj < 4; ++jj) acc[i][jj] += a[i] * bb[jj];
    }
    __syncthreads();
  }
  for (int i = 0; i < 4; ++i){
    int gi = i0 + ty * 4 + i;
    for (int jj = 0; jj < 4; ++jj){
      int gn = n0 + tx * 4 + jj; if (gn >= NCHUNK) continue;
      float v = acc[i][jj] * LOGIT_SCALE;
      if (chunkden[b * NCHUNK + gn] <= 0.f) v = -FLT_MAX;
      logits[((long)b * QN + gi) * NCHUNK + gn] = v;
    }
  }
}

// ---------------- top-8 + softmax weights, one wave per (b,i) row ----------------
__global__ __launch_bounds__(64) void topk_kernel(const float* __restrict__ logits,
                                                  int* __restrict__ topi_out,
                                                  float* __restrict__ wts_out){
  int row = blockIdx.x;   // b*128+i
  __shared__ float lds[NCHUNK];
  __shared__ float topv[TOPKK];
  __shared__ int   topi[TOPKK];
  int lane = threadIdx.x;
  for (int idx = lane; idx < NCHUNK; idx += 64) lds[idx] = logits[(long)row * NCHUNK + idx];
  __syncthreads();
  for (int it = 0; it < TOPKK; ++it){
    float bv = -INFINITY; int bi = 0x7fffffff;
    for (int idx = lane; idx < NCHUNK; idx += 64){
      float v = lds[idx];
      if (v > bv){ bv = v; bi = idx; }   // increasing idx => first occurrence kept on ties
    }
    for (int d = 32; d >= 1; d >>= 1){
      float ov = __shfl_xor(bv, d, 64);
      int   oi = __shfl_xor(bi, d, 64);
      if (ov > bv || (ov == bv && oi < bi)){ bv = ov; bi = oi; }
    }
    if (lane == 0){ topv[it] = bv; topi[it] = bi; lds[bi] = -INFINITY; }
    __syncthreads();
  }
  if (lane == 0){
    float m = topv[0];
    for (int r = 1; r < TOPKK; ++r) m = fmaxf(m, topv[r]);
    float e[TOPKK], s = 0.f;
    for (int r = 0; r < TOPKK; ++r){ e[r] = expf(topv[r] - m); s += e[r]; }
    for (int r = 0; r < TOPKK; ++r){
      wts_out[(long)row * TOPKK + r] = e[r] / s;
      topi_out[(long)row * TOPKK + r] = topi[r];
    }
  }
}

// ---------------- KV projection (per batch): (mem+pos)[20000x512] @ kv_w[512x1024] -> bf16 ----------------
__global__ __launch_bounds__(256) void kv_kernel(const float* __restrict__ mem,
                                                 const float* __restrict__ kvw,
                                                 const float* __restrict__ pos,
                                                 unsigned short* __restrict__ kvout){
  __shared__ short As[128][40];   // [m][k], 80B rows (16B aligned)
  __shared__ short Bt[128][40];   // [n][k]
  int m0 = blockIdx.x * 128, n0 = blockIdx.y * 128;
  int tid = threadIdx.x;
  int wid = tid >> 6, lane = tid & 63;
  int wr = wid >> 1, wc = wid & 1;
  int lr = lane & 15, lg = lane >> 4;
  f32x4 zero = 0.f;
  f32x4 acc[4][4];
  for (int mi = 0; mi < 4; ++mi) for (int ni = 0; ni < 4; ++ni) acc[mi][ni] = zero;
  for (int k0 = 0; k0 < HID; k0 += 32){
    for (int idx = tid; idx < 128 * 32; idx += 256){
      int r = idx >> 5, c = idx & 31;
      int gr = m0 + r;
      float v = 0.f;
      if (gr < NMEM) v = mem[(long)gr * HID + k0 + c] + pos[(gr & 31) * HID + k0 + c];
      As[r][c] = f2bf(v);
    }
    for (int idx = tid; idx < 32 * 128; idx += 256){
      int kk = idx >> 7, n = idx & 127;
      Bt[n][kk] = f2bf(kvw[(long)(k0 + kk) * NKV + n0 + n]);
    }
    __syncthreads();
    bf16x8 af[4], bfr[4];
#pragma unroll
    for (int mi = 0; mi < 4; ++mi) af[mi]  = *(const bf16x8*)&As[wr * 64 + mi * 16 + lr][lg * 8];
#pragma unroll
    for (int ni = 0; ni < 4; ++ni) bfr[ni] = *(const bf16x8*)&Bt[wc * 64 + ni * 16 + lr][lg * 8];
#pragma unroll
    for (int mi = 0; mi < 4; ++mi)
#pragma unroll
      for (int ni = 0; ni < 4; ++ni)
        acc[mi][ni] = __builtin_amdgcn_mfma_f32_16x16x32_bf16(af[mi], bfr[ni], acc[mi][ni], 0, 0, 0);
    __syncthreads();
  }
  for (int mi = 0; mi < 4; ++mi)
    for (int ni = 0; ni < 4; ++ni)
      for (int rr = 0; rr < 4; ++rr){
        int gr = m0 + wr * 64 + mi * 16 + lg * 4 + rr;
        int gn = n0 + wc * 64 + ni * 16 + lr;
        if (gr < NMEM) kvout[(long)gr * NKV + gn] = (unsigned short)f2bf(acc[mi][ni][rr]);
      }
}

// ---------------- attention per (i, k-slot) for one batch ----------------
__global__ __launch_bounds__(256) void attn_kernel(const float* __restrict__ qh,
                                                   const unsigned short* __restrict__ kv,
                                                   const int* __restrict__ topidx,
                                                   const float* __restrict__ wts,
                                                   const void* __restrict__ mask,
                                                   const int* __restrict__ flagp,
                                                   float* __restrict__ osc,
                                                   int bb){
  int bx = blockIdx.x;
  int i = bx >> 3, k = bx & 7;
  int t = threadIdx.x;
  __shared__ float qs[HID];
  __shared__ float att[HEADS][CHUNK + 1];
  long sel = ((long)(bb * QN + i)) * TOPKK + k;
  int chunk = topidx[sel];
  float w8 = wts[sel];
  const float* qrow = qh + ((long)(bb * QN + i)) * HID;
  qs[t] = qrow[t]; qs[t + 256] = qrow[t + 256];
  __syncthreads();
  int flag = *flagp;
  int h = t >> 5, c = t & 31;
  // sim
  const unsigned short* krow = kv + ((long)(chunk * CHUNK + c)) * NKV + h * DHEAD;
  float s = 0.f;
  for (int e = 0; e < DHEAD; ++e) s += qs[h * DHEAD + e] * bf2f(krow[e]);
  bool mv = mask_at(mask, flag, (long)bb * NMEM + (long)chunk * CHUNK + c);
  if (!mv) s = -FLT_MAX;
  float m = s;
  for (int d = 16; d >= 1; d >>= 1) m = fmaxf(m, __shfl_xor(m, d, 32));
  float p = expf(s - m);
  float su = p;
  for (int d = 16; d >= 1; d >>= 1) su += __shfl_xor(su, d, 32);
  att[h][c] = p / su;
  __syncthreads();
  // o: thread -> (h, 2 e's)
  int e0 = (t & 31) * 2;
  float o0 = 0.f, o1 = 0.f;
  for (int c2 = 0; c2 < CHUNK; ++c2){
    float a = att[h][c2];
    const unsigned short* vr = kv + ((long)(chunk * CHUNK + c2)) * NKV + 512 + h * DHEAD + e0;
    o0 += a * bf2f(vr[0]);
    o1 += a * bf2f(vr[1]);
  }
  long ob = (((long)(bb * QN + i) * TOPKK) + k) * HID + h * DHEAD + e0;
  osc[ob]     = o0 * w8;
  osc[ob + 1] = o1 * w8;
}

// ---------------- final: reduce over k, then @ (out_w@fc2_w) + folded bias ----------------
__global__ __launch_bounds__(512) void final_kernel(const float* __restrict__ osc,
                                                    const float* __restrict__ Wf,
                                                    const float* __restrict__ bfold,
                                                    float* __restrict__ out){
  int bi = blockIdx.x;   // b*128+i
  int t = threadIdx.x;
  __shared__ float lds[HID];
  float s = 0.f;
  for (int k = 0; k < TOPKK; ++k) s += osc[(((long)bi * TOPKK) + k) * HID + t];
  lds[t] = s;
  __syncthreads();
  if (t < 5){
    float a = bfold[t];
    for (int d = 0; d < HID; ++d) a += lds[d] * Wf[d * 5 + t];
    out[bi * 5 + t] = a;
  }
}

extern "C" void kernel_launch(void* const* d_in, const int* in_sizes, int n_in,
                              void* d_out, int out_size, void* d_ws, size_t ws_size,
                              hipStream_t stream) {
  const float* queries  = (const float*)d_in[1];
  const float* memories = (const float*)d_in[2];
  const void*  mask     = d_in[3];
  const float* sq_w = (const float*)d_in[10];
  const float* sq_b = (const float*)d_in[11];
  const float* sk_w = (const float*)d_in[12];
  const float* sk_b = (const float*)d_in[13];
  const float* q_w  = (const float*)d_in[14];
  const float* kv_w = (const float*)d_in[15];
  const float* out_w = (const float*)d_in[16];
  const float* out_b = (const float*)d_in[17];
  const float* fc2_w = (const float*)d_in[18];
  const float* fc2_b = (const float*)d_in[19];
  float* out = (float*)d_out;

  char* ws = (char*)d_ws;
  size_t o_sum  = 0;                       // 4*625*512 f32 = 5,120,000
  size_t o_sk   = o_sum + 5120000;         // 5,120,000
  size_t o_sq   = o_sk  + 5120000;         // 1,048,576
  size_t o_qh   = o_sq  + 1048576;         // 1,048,576
  size_t o_log  = o_qh  + 1048576;         // 1,280,000
  size_t o_den  = o_log + 1280000;         // 10,240
  size_t o_pos  = o_den + 10240;           // 65,536
  size_t o_wf   = o_pos + 65536;           // 10,240
  size_t o_bf   = o_wf  + 10240;           // 512
  size_t o_ti   = o_bf  + 512;             // 16,384
  size_t o_wt   = o_ti  + 16384;           // 16,384
  size_t o_osc  = o_wt  + 16384;           // 8,388,608
  size_t o_flag = o_osc + 8388608;         // 512
  size_t o_kv   = o_flag + 512;            // 40,960,000 (bf16, per-batch reuse)

  float* summ  = (float*)(ws + o_sum);
  float* sk    = (float*)(ws + o_sk);
  float* sq    = (float*)(ws + o_sq);
  float* qh    = (float*)(ws + o_qh);
  float* logit = (float*)(ws + o_log);
  float* den   = (float*)(ws + o_den);
  float* pos   = (float*)(ws + o_pos);
  float* Wf    = (float*)(ws + o_wf);
  float* bfold = (float*)(ws + o_bf);
  int*   ti    = (int*)  (ws + o_ti);
  float* wt    = (float*)(ws + o_wt);
  float* osc   = (float*)(ws + o_osc);
  int*   flagp = (int*)  (ws + o_flag);
  unsigned short* kvbuf = (unsigned short*)(ws + o_kv);

  misc_kernel<<<dim3(32), dim3(512), 0, stream>>>(pos, flagp, mask);
  fold_kernel<<<dim3(5), dim3(512), 0, stream>>>(out_w, out_b, fc2_w, fc2_b, Wf, bfold);
  sum_kernel<<<dim3(NB * NCHUNK), dim3(512), 0, stream>>>(memories, mask, flagp, summ, den);

  // selection path in f32 (top-k is discrete; keep it numerically exact vs np)
  gemm_f32<<<dim3(40, 8), dim3(256), 0, stream>>>(summ, sk_w, sk_b, sk, NB * NCHUNK, HID, HID, 1.0f);
  gemm_f32<<<dim3(8, 8), dim3(256), 0, stream>>>(queries, sq_w, sq_b, sq, NB * QN, HID, HID, 1.0f);
  gemm_f32<<<dim3(8, 8), dim3(256), 0, stream>>>(queries, q_w, nullptr, qh, NB * QN, HID, HID, 0.125f);
  logits_kernel<<<dim3(10, 2, NB), dim3(256), 0, stream>>>(sq, sk, den, logit);
  topk_kernel<<<dim3(NB * QN), dim3(64), 0, stream>>>(logit, ti, wt);

  for (int bb = 0; bb < NB; ++bb){
    const float* memb = memories + (long)bb * NMEM * HID;
    kv_kernel<<<dim3(157, 8), dim3(256), 0, stream>>>(memb, kv_w, pos, kvbuf);
    attn_kernel<<<dim3(QN * TOPKK), dim3(256), 0, stream>>>(qh, kvbuf, ti, wt, mask, flagp, osc, bb);
  }
  final_kernel<<<dim3(NB * QN), dim3(512), 0, stream>>>(osc, Wf, bfold, out);
}

// Round 2
// 741.270 us; speedup vs baseline: 1.9392x; 1.9392x over previous
//
#include <hip/hip_runtime.h>
#include <hip/hip_bf16.h>
#include <float.h>
#include <math.h>

// Problem constants
#define NB      4
#define QN      128
#define HID     512
#define NMEM    20000
#define MPAD    20096    // 157*128
#define NCHUNK  625
#define CHUNK   32
#define HEADS   8
#define DHEAD   64
#define TOPKK   8
#define NKV     1024   // 2*HEADS*DHEAD
#define LOGIT_SCALE 0.044194173824159216f  // 512^-0.5

typedef __attribute__((ext_vector_type(8))) short bf16x8;
typedef __attribute__((ext_vector_type(4))) float f32x4;

__device__ __forceinline__ short f2bf(float f){
  __hip_bfloat16 h = __float2bfloat16(f);
  return *reinterpret_cast<short*>(&h);
}
__device__ __forceinline__ float bf2f(unsigned short s){
  __hip_bfloat16 h;
  *reinterpret_cast<unsigned short*>(&h) = s;
  return __bfloat162float(h);
}
__device__ __forceinline__ bool mask_at(const void* m, int flag, long i){
  return flag ? (((const unsigned char*)m)[i] != 0)
              : (((const int*)m)[i] != 0);
}
__device__ __forceinline__ void gload16(const void* g, void* l){
  __builtin_amdgcn_global_load_lds((const __attribute__((address_space(1))) void*)g,
                                   (__attribute__((address_space(3))) void*)l, 16, 0, 0);
}

// ---------------- misc: pos table + mask-layout flag ----------------
__global__ __launch_bounds__(512) void misc_kernel(float* __restrict__ pos,
                                                   int* __restrict__ flagp,
                                                   const void* __restrict__ mask){
  int c = blockIdx.x;      // 0..31
  int d = threadIdx.x;     // 0..511
  int j = (d < 256) ? d : d - 256;
  float invf = expf(-((2.0f * (float)j) / 512.0f) * 9.2103403719761836f);
  float arg = (float)(31 - c) * invf;
  pos[c * 512 + d] = (d < 256) ? sinf(arg) : cosf(arg);
  if (c == 0 && d == 0){
    const unsigned char* mb = (const unsigned char*)mask;
    *flagp = (mb[1] != 0) ? 1 : 0;
  }
}

// ---------------- fold out_w @ fc2_w ----------------
__global__ __launch_bounds__(512) void fold_kernel(const float* __restrict__ out_w,
                                                   const float* __restrict__ out_b,
                                                   const float* __restrict__ fc2_w,
                                                   const float* __restrict__ fc2_b,
                                                   float* __restrict__ Wf,
                                                   float* __restrict__ bf){
  int j = blockIdx.x;   // 0..4
  int d = threadIdx.x;  // 0..511
  float s = 0.f;
  for (int k = 0; k < 512; ++k) s += out_w[d * 512 + k] * fc2_w[k * 5 + j];
  Wf[d * 5 + j] = s;
  if (d == 0){
    float sb = 0.f;
    for (int k = 0; k < 512; ++k) sb += out_b[k] * fc2_w[k * 5 + j];
    bf[j] = sb + fc2_b[j];
  }
}

// ---------------- kv_w transpose -> bf16 Bt[1024][512] ----------------
__global__ __launch_bounds__(256) void wtr_kernel(const float* __restrict__ kvw,
                                                  unsigned short* __restrict__ Bt){
  long id = (long)blockIdx.x * 256 + threadIdx.x;   // 524288 total
  int n = (int)(id >> 9), k = (int)(id & 511);
  Bt[id] = (unsigned short)f2bf(kvw[(long)k * NKV + n]);
}

// ---------------- prep: (mem+pos) -> bf16 A[MPAD][512], pad rows zero ----------------
__global__ __launch_bounds__(256) void prep_kernel(const float* __restrict__ mem,
                                                   const float* __restrict__ pos,
                                                   unsigned short* __restrict__ Abf){
  long idx = (long)blockIdx.x * 256 + threadIdx.x;  // MPAD*512/4 = 2,572,288
  int r = (int)(idx >> 7);
  int cv = (int)(idx & 127) << 2;
  ushort4 o;
  if (r < NMEM){
    float4 m4 = *(const float4*)(mem + (long)r * 512 + cv);
    float4 p4 = *(const float4*)(pos + (r & 31) * 512 + cv);
    o.x = (unsigned short)f2bf(m4.x + p4.x);
    o.y = (unsigned short)f2bf(m4.y + p4.y);
    o.z = (unsigned short)f2bf(m4.z + p4.z);
    o.w = (unsigned short)f2bf(m4.w + p4.w);
  } else {
    o.x = o.y = o.z = o.w = 0;
  }
  *(ushort4*)(Abf + idx * 4) = o;
}

// ---------------- chunk summarize ----------------
__global__ __launch_bounds__(512) void sum_kernel(const float* __restrict__ memories,
                                                  const void* __restrict__ mask,
                                                  const int* __restrict__ flagp,
                                                  float* __restrict__ summ,
                                                  float* __restrict__ chunkden){
  int blk = blockIdx.x;              // 0..2499 = b*625+n
  int b = blk / NCHUNK, n = blk % NCHUNK;
  int t = threadIdx.x;
  int flag = *flagp;
  long mbase = (long)b * NMEM + (long)n * CHUNK;
  float den = 0.f;
  for (int c = 0; c < CHUNK; ++c) den += mask_at(mask, flag, mbase + c) ? 1.f : 0.f;
  const float* rowb = memories + mbase * HID;
  float s = 0.f;
  for (int c = 0; c < CHUNK; ++c){
    if (mask_at(mask, flag, mbase + c)) s += rowb[(long)c * HID + t];
  }
  summ[(long)blk * HID + t] = s / (den + 1e-5f);
  if (t == 0) chunkden[blk] = den;
}

// ---------------- generic f32 GEMM: C[MxN] = A[MxK] @ B[KxN] (*scale, +bias) ----------------
__global__ __launch_bounds__(256) void gemm_f32(const float* __restrict__ A,
                                                const float* __restrict__ B,
                                                const float* __restrict__ bias,
                                                float* __restrict__ C,
                                                int M, int N, int K, float scale){
  __shared__ float As[16][65];
  __shared__ float Bs[16][65];
  int tx = threadIdx.x & 15, ty = threadIdx.x >> 4;
  int m0 = blockIdx.x * 64, n0 = blockIdx.y * 64;
  float acc[4][4] = {};
  for (int k0 = 0; k0 < K; k0 += 16){
    for (int idx = threadIdx.x; idx < 64 * 16; idx += 256){
      int r = idx >> 4, c = idx & 15;
      int gm = m0 + r;
      As[c][r] = (gm < M) ? A[(long)gm * K + k0 + c] : 0.f;
    }
    for (int idx = threadIdx.x; idx < 16 * 64; idx += 256){
      int r = idx >> 6, c = idx & 63;
      int gn = n0 + c;
      Bs[r][c] = (gn < N) ? B[(long)(k0 + r) * N + gn] : 0.f;
    }
    __syncthreads();
#pragma unroll
    for (int kk = 0; kk < 16; ++kk){
      float a[4], bb[4];
#pragma unroll
      for (int u = 0; u < 4; ++u){ a[u] = As[kk][ty * 4 + u]; bb[u] = Bs[kk][tx * 4 + u]; }
#pragma unroll
      for (int i = 0; i < 4; ++i)
#pragma unroll
        for (int jj = 0; jj < 4; ++jj) acc[i][jj] += a[i] * bb[jj];
    }
    __syncthreads();
  }
  for (int i = 0; i < 4; ++i){
    int gm = m0 + ty * 4 + i; if (gm >= M) continue;
    for (int jj = 0; jj < 4; ++jj){
      int gn = n0 + tx * 4 + jj; if (gn >= N) continue;
      float v = acc[i][jj] * scale;
      if (bias) v += bias[gn];
      C[(long)gm * N + gn] = v;
    }
  }
}

// ---------------- logits: per batch sq(128xK) @ sk(625xK)^T * scale, mask-any ----------------
__global__ __launch_bounds__(256) void logits_kernel(const float* __restrict__ sq,
                                                     const float* __restrict__ sk,
                                                     const float* __restrict__ chunkden,
                                                     float* __restrict__ logits){
  int b = blockIdx.z;
  int n0 = blockIdx.x * 64, i0 = blockIdx.y * 64;
  const float* A = sq + (long)b * QN * HID;
  const float* B = sk + (long)b * NCHUNK * HID;
  __shared__ float As[16][65];
  __shared__ float Bs[16][65];
  int tx = threadIdx.x & 15, ty = threadIdx.x >> 4;
  float acc[4][4] = {};
  for (int k0 = 0; k0 < HID; k0 += 16){
    for (int idx = threadIdx.x; idx < 64 * 16; idx += 256){
      int r = idx >> 4, c = idx & 15;
      As[c][r] = A[(long)(i0 + r) * HID + k0 + c];
    }
    for (int idx = threadIdx.x; idx < 64 * 16; idx += 256){
      int r = idx >> 4, c = idx & 15;
      int gn = n0 + r;
      Bs[c][r] = (gn < NCHUNK) ? B[(long)gn * HID + k0 + c] : 0.f;
    }
    __syncthreads();
#pragma unroll
    for (int kk = 0; kk < 16; ++kk){
      float a[4], bb[4];
#pragma unroll
      for (int u = 0; u < 4; ++u){ a[u] = As[kk][ty * 4 + u]; bb[u] = Bs[kk][tx * 4 + u]; }
#pragma unroll
      for (int i = 0; i < 4; ++i)
#pragma unroll
        for (int jj = 0; jj < 4; ++jj) acc[i][jj] += a[i] * bb[jj];
    }
    __syncthreads();
  }
  for (int i = 0; i < 4; ++i){
    int gi = i0 + ty * 4 + i;
    for (int jj = 0; jj < 4; ++jj){
      int gn = n0 + tx * 4 + jj; if (gn >= NCHUNK) continue;
      float v = acc[i][jj] * LOGIT_SCALE;
      if (chunkden[b * NCHUNK + gn] <= 0.f) v = -FLT_MAX;
      logits[((long)b * QN + gi) * NCHUNK + gn] = v;
    }
  }
}

// ---------------- top-8 + softmax weights, one wave per (b,i) row ----------------
__global__ __launch_bounds__(64) void topk_kernel(const float* __restrict__ logits,
                                                  int* __restrict__ topi_out,
                                                  float* __restrict__ wts_out){
  int row = blockIdx.x;   // b*128+i
  __shared__ float lds[NCHUNK];
  __shared__ float topv[TOPKK];
  __shared__ int   topi[TOPKK];
  int lane = threadIdx.x;
  for (int idx = lane; idx < NCHUNK; idx += 64) lds[idx] = logits[(long)row * NCHUNK + idx];
  __syncthreads();
  for (int it = 0; it < TOPKK; ++it){
    float bv = -INFINITY; int bi = 0x7fffffff;
    for (int idx = lane; idx < NCHUNK; idx += 64){
      float v = lds[idx];
      if (v > bv){ bv = v; bi = idx; }
    }
    for (int d = 32; d >= 1; d >>= 1){
      float ov = __shfl_xor(bv, d, 64);
      int   oi = __shfl_xor(bi, d, 64);
      if (ov > bv || (ov == bv && oi < bi)){ bv = ov; bi = oi; }
    }
    if (lane == 0){ topv[it] = bv; topi[it] = bi; lds[bi] = -INFINITY; }
    __syncthreads();
  }
  if (lane == 0){
    float m = topv[0];
    for (int r = 1; r < TOPKK; ++r) m = fmaxf(m, topv[r]);
    float e[TOPKK], s = 0.f;
    for (int r = 0; r < TOPKK; ++r){ e[r] = expf(topv[r] - m); s += e[r]; }
    for (int r = 0; r < TOPKK; ++r){
      wts_out[(long)row * TOPKK + r] = e[r] / s;
      topi_out[(long)row * TOPKK + r] = topi[r];
    }
  }
}

// ---------------- KV GEMM (m97 structure): A[MPAD][512]bf16 @ Bt[1024][512]bf16^T -> kv bf16 ----------------
// grid: 157*8 blocks; id>>3 = row panel, id&7 = n block. 256 thr = 4 waves, each wave 64x64.
__global__ __launch_bounds__(256) void kv_gemm(const unsigned short* __restrict__ A,
                                               const unsigned short* __restrict__ Bt,
                                               unsigned short* __restrict__ kvout){
  __shared__ unsigned short As[128 * 32];   // 8 KB, rows of 64B (linear, gload_lds order)
  __shared__ unsigned short Bs[128 * 32];   // 8 KB
  int id = blockIdx.x;
  int panel = id >> 3, nb = id & 7;
  int m0 = panel << 7, n0 = nb << 7;
  int tid = threadIdx.x;
  int wid = tid >> 6, lane = tid & 63;
  int wr = wid >> 1, wc = wid & 1;
  int lr = lane & 15, lg = lane >> 4;

  // staging: wave-load = 64 lanes x 16B = 16 rows of 64B; 2 rounds each for A and B
  int srow = wid * 16 + (lane >> 2);
  int scol = (lane & 3) << 3;                     // element col
  const unsigned short* gA0 = A  + (long)(m0 + srow) * 512 + scol;
  const unsigned short* gA1 = gA0 + 64 * 512;
  const unsigned short* gB0 = Bt + (long)(n0 + srow) * 512 + scol;
  const unsigned short* gB1 = gB0 + 64 * 512;
  unsigned short* lA0 = &As[(wid * 16) * 32];
  unsigned short* lA1 = &As[(64 + wid * 16) * 32];
  unsigned short* lB0 = &Bs[(wid * 16) * 32];
  unsigned short* lB1 = &Bs[(64 + wid * 16) * 32];

  f32x4 acc[4][4];
#pragma unroll
  for (int i = 0; i < 4; ++i)
#pragma unroll
    for (int j = 0; j < 4; ++j) acc[i][j] = (f32x4)0.f;

  for (int k0 = 0; k0 < 512; k0 += 32){
    gload16(gA0 + k0, lA0);
    gload16(gA1 + k0, lA1);
    gload16(gB0 + k0, lB0);
    gload16(gB1 + k0, lB1);
    __syncthreads();
    bf16x8 af[4], bfv[4];
#pragma unroll
    for (int mi = 0; mi < 4; ++mi) af[mi]  = *(const bf16x8*)&As[(wr * 64 + mi * 16 + lr) * 32 + lg * 8];
#pragma unroll
    for (int ni = 0; ni < 4; ++ni) bfv[ni] = *(const bf16x8*)&Bs[(wc * 64 + ni * 16 + lr) * 32 + lg * 8];
#pragma unroll
    for (int mi = 0; mi < 4; ++mi)
#pragma unroll
      for (int ni = 0; ni < 4; ++ni)
        acc[mi][ni] = __builtin_amdgcn_mfma_f32_16x16x32_bf16(af[mi], bfv[ni], acc[mi][ni], 0, 0, 0);
    __syncthreads();
  }
#pragma unroll
  for (int mi = 0; mi < 4; ++mi)
#pragma unroll
    for (int ni = 0; ni < 4; ++ni)
#pragma unroll
      for (int rr = 0; rr < 4; ++rr){
        int gr = m0 + wr * 64 + mi * 16 + lg * 4 + rr;
        int gn = n0 + wc * 64 + ni * 16 + lr;
        kvout[(long)gr * NKV + gn] = (unsigned short)f2bf(acc[mi][ni][rr]);
      }
}

// ---------------- attention per (i, k-slot) for one batch ----------------
__global__ __launch_bounds__(256) void attn_kernel(const float* __restrict__ qh,
                                                   const unsigned short* __restrict__ kv,
                                                   const int* __restrict__ topidx,
                                                   const float* __restrict__ wts,
                                                   const void* __restrict__ mask,
                                                   const int* __restrict__ flagp,
                                                   float* __restrict__ osc,
                                                   int bb){
  int bx = blockIdx.x;
  int i = bx >> 3, k = bx & 7;
  int t = threadIdx.x;
  __shared__ float qs[HID];
  __shared__ float att[HEADS][CHUNK + 1];
  long sel = ((long)(bb * QN + i)) * TOPKK + k;
  int chunk = topidx[sel];
  float w8 = wts[sel];
  const float* qrow = qh + ((long)(bb * QN + i)) * HID;
  qs[t] = qrow[t]; qs[t + 256] = qrow[t + 256];
  __syncthreads();
  int flag = *flagp;
  int h = t >> 5, c = t & 31;
  // sim: 16B vectorized K reads
  const unsigned short* krow = kv + ((long)(chunk * CHUNK + c)) * NKV + h * DHEAD;
  float s = 0.f;
#pragma unroll
  for (int e8 = 0; e8 < 8; ++e8){
    bf16x8 k8 = *(const bf16x8*)(krow + e8 * 8);
#pragma unroll
    for (int j = 0; j < 8; ++j) s += qs[h * DHEAD + e8 * 8 + j] * bf2f((unsigned short)k8[j]);
  }
  bool mv = mask_at(mask, flag, (long)bb * NMEM + (long)chunk * CHUNK + c);
  if (!mv) s = -FLT_MAX;
  float m = s;
  for (int d = 16; d >= 1; d >>= 1) m = fmaxf(m, __shfl_xor(m, d, 32));
  float p = expf(s - m);
  float su = p;
  for (int d = 16; d >= 1; d >>= 1) su += __shfl_xor(su, d, 32);
  att[h][c] = p / su;
  __syncthreads();
  // o: thread -> (h, 2 e's); coalesced across lanes per c2
  int e0 = (t & 31) * 2;
  float o0 = 0.f, o1 = 0.f;
#pragma unroll 4
  for (int c2 = 0; c2 < CHUNK; ++c2){
    float a = att[h][c2];
    const unsigned short* vr = kv + ((long)(chunk * CHUNK + c2)) * NKV + 512 + h * DHEAD + e0;
    o0 += a * bf2f(vr[0]);
    o1 += a * bf2f(vr[1]);
  }
  long ob = (((long)(bb * QN + i) * TOPKK) + k) * HID + h * DHEAD + e0;
  osc[ob]     = o0 * w8;
  osc[ob + 1] = o1 * w8;
}

// ---------------- final: reduce over k, then @ (out_w@fc2_w) + folded bias ----------------
__global__ __launch_bounds__(512) void final_kernel(const float* __restrict__ osc,
                                                    const float* __restrict__ Wf,
                                                    const float* __restrict__ bfold,
                                                    float* __restrict__ out){
  int bi = blockIdx.x;   // b*128+i
  int t = threadIdx.x;
  __shared__ float lds[HID];
  float s = 0.f;
  for (int k = 0; k < TOPKK; ++k) s += osc[(((long)bi * TOPKK) + k) * HID + t];
  lds[t] = s;
  __syncthreads();
  if (t < 5){
    float a = bfold[t];
    for (int d = 0; d < HID; ++d) a += lds[d] * Wf[d * 5 + t];
    out[bi * 5 + t] = a;
  }
}

extern "C" void kernel_launch(void* const* d_in, const int* in_sizes, int n_in,
                              void* d_out, int out_size, void* d_ws, size_t ws_size,
                              hipStream_t stream) {
  const float* queries  = (const float*)d_in[1];
  const float* memories = (const float*)d_in[2];
  const void*  mask     = d_in[3];
  const float* sq_w = (const float*)d_in[10];
  const float* sq_b = (const float*)d_in[11];
  const float* sk_w = (const float*)d_in[12];
  const float* sk_b = (const float*)d_in[13];
  const float* q_w  = (const float*)d_in[14];
  const float* kv_w = (const float*)d_in[15];
  const float* out_w = (const float*)d_in[16];
  const float* out_b = (const float*)d_in[17];
  const float* fc2_w = (const float*)d_in[18];
  const float* fc2_b = (const float*)d_in[19];
  float* out = (float*)d_out;

  char* ws = (char*)d_ws;
  size_t o_sum  = 0;                        // 5,120,000
  size_t o_sk   = o_sum + 5120000;          // 5,120,000
  size_t o_sq   = o_sk  + 5120000;          // 1,048,576
  size_t o_qh   = o_sq  + 1048576;          // 1,048,576
  size_t o_log  = o_qh  + 1048576;          // 1,280,000
  size_t o_den  = o_log + 1280000;          // 10,240
  size_t o_pos  = o_den + 10240;            // 65,536
  size_t o_wf   = o_pos + 65536;            // 10,240
  size_t o_bf   = o_wf  + 10240;            // 512
  size_t o_ti   = o_bf  + 512;              // 16,384
  size_t o_wt   = o_ti  + 16384;            // 16,384
  size_t o_osc  = o_wt  + 16384;            // 8,388,608
  size_t o_flag = o_osc + 8388608;          // 512
  size_t o_abf  = o_flag + 512;             // 20,578,304 (MPAD*512*2)
  size_t o_bt   = o_abf + 20578304;         // 1,048,576
  size_t o_kv   = o_bt  + 1048576;          // 41,156,608 (MPAD*1024*2, per-batch reuse)

  float* summ  = (float*)(ws + o_sum);
  float* sk    = (float*)(ws + o_sk);
  float* sq    = (float*)(ws + o_sq);
  float* qh    = (float*)(ws + o_qh);
  float* logit = (float*)(ws + o_log);
  float* den   = (float*)(ws + o_den);
  float* pos   = (float*)(ws + o_pos);
  float* Wf    = (float*)(ws + o_wf);
  float* bfold = (float*)(ws + o_bf);
  int*   ti    = (int*)  (ws + o_ti);
  float* wt    = (float*)(ws + o_wt);
  float* osc   = (float*)(ws + o_osc);
  int*   flagp = (int*)  (ws + o_flag);
  unsigned short* abf   = (unsigned short*)(ws + o_abf);
  unsigned short* btw   = (unsigned short*)(ws + o_bt);
  unsigned short* kvbuf = (unsigned short*)(ws + o_kv);

  misc_kernel<<<dim3(32), dim3(512), 0, stream>>>(pos, flagp, mask);
  fold_kernel<<<dim3(5), dim3(512), 0, stream>>>(out_w, out_b, fc2_w, fc2_b, Wf, bfold);
  wtr_kernel<<<dim3(2048), dim3(256), 0, stream>>>(kv_w, btw);
  sum_kernel<<<dim3(NB * NCHUNK), dim3(512), 0, stream>>>(memories, mask, flagp, summ, den);

  // selection path in f32 (top-k is discrete; keep it numerically exact vs np)
  gemm_f32<<<dim3(40, 8), dim3(256), 0, stream>>>(summ, sk_w, sk_b, sk, NB * NCHUNK, HID, HID, 1.0f);
  gemm_f32<<<dim3(8, 8), dim3(256), 0, stream>>>(queries, sq_w, sq_b, sq, NB * QN, HID, HID, 1.0f);
  gemm_f32<<<dim3(8, 8), dim3(256), 0, stream>>>(queries, q_w, nullptr, qh, NB * QN, HID, HID, 0.125f);
  logits_kernel<<<dim3(10, 2, NB), dim3(256), 0, stream>>>(sq, sk, den, logit);
  topk_kernel<<<dim3(NB * QN), dim3(64), 0, stream>>>(logit, ti, wt);

  for (int bb = 0; bb < NB; ++bb){
    const float* memb = memories + (long)bb * NMEM * HID;
    prep_kernel<<<dim3(10048), dim3(256), 0, stream>>>(memb, pos, abf);
    kv_gemm<<<dim3(157 * 8), dim3(256), 0, stream>>>(abf, btw, kvbuf);
    attn_kernel<<<dim3(QN * TOPKK), dim3(256), 0, stream>>>(qh, kvbuf, ti, wt, mask, flagp, osc, bb);
  }
  final_kernel<<<dim3(NB * QN), dim3(512), 0, stream>>>(osc, Wf, bfold, out);
}

// Round 3
// 638.962 us; speedup vs baseline: 2.2497x; 1.1601x over previous
//
#include <hip/hip_runtime.h>
#include <hip/hip_bf16.h>
#include <float.h>
#include <math.h>

// Problem constants
#define NB      4
#define QN      128
#define HID     512
#define NMEM    20000
#define MPAD    20096    // 157*128
#define NCHUNK  625
#define CHUNK   32
#define HEADS   8
#define DHEAD   64
#define TOPKK   8
#define NKV     1024   // 2*HEADS*DHEAD
#define LOGIT_SCALE 0.044194173824159216f  // 512^-0.5
#define W2LD    576    // W2buf / u_ext leading dim (512 + 1 alpha col + pad)
#define STROWS  520    // summText rows: 512 + ones row + 7 zero rows
#define LGLD    640    // logits leading dim

typedef __attribute__((ext_vector_type(8))) short bf16x8;
typedef __attribute__((ext_vector_type(4))) float f32x4;

__device__ __forceinline__ short f2bf(float f){
  __hip_bfloat16 h = __float2bfloat16(f);
  return *reinterpret_cast<short*>(&h);
}
__device__ __forceinline__ float bf2f(unsigned short s){
  __hip_bfloat16 h;
  *reinterpret_cast<unsigned short*>(&h) = s;
  return __bfloat162float(h);
}
__device__ __forceinline__ bool mask_at(const void* m, int flag, long i){
  return flag ? (((const unsigned char*)m)[i] != 0)
              : (((const int*)m)[i] != 0);
}
__device__ __forceinline__ void gload16(const void* g, void* l){
  __builtin_amdgcn_global_load_lds((const __attribute__((address_space(1))) void*)g,
                                   (__attribute__((address_space(3))) void*)l, 16, 0, 0);
}

// ---------------- misc: pos table + mask-layout flag ----------------
__global__ __launch_bounds__(512) void misc_kernel(float* __restrict__ pos,
                                                   int* __restrict__ flagp,
                                                   const void* __restrict__ mask){
  int c = blockIdx.x;      // 0..31
  int d = threadIdx.x;     // 0..511
  int j = (d < 256) ? d : d - 256;
  float invf = expf(-((2.0f * (float)j) / 512.0f) * 9.2103403719761836f);
  float arg = (float)(31 - c) * invf;
  pos[c * 512 + d] = (d < 256) ? sinf(arg) : cosf(arg);
  if (c == 0 && d == 0){
    const unsigned char* mb = (const unsigned char*)mask;
    *flagp = (mb[1] != 0) ? 1 : 0;
  }
}

// ---------------- fold out_w @ fc2_w ----------------
__global__ __launch_bounds__(512) void fold_kernel(const float* __restrict__ out_w,
                                                   const float* __restrict__ out_b,
                                                   const float* __restrict__ fc2_w,
                                                   const float* __restrict__ fc2_b,
                                                   float* __restrict__ Wf,
                                                   float* __restrict__ bf){
  int j = blockIdx.x;   // 0..4
  int d = threadIdx.x;  // 0..511
  float s = 0.f;
  for (int k = 0; k < 512; ++k) s += out_w[d * 512 + k] * fc2_w[k * 5 + j];
  Wf[d * 5 + j] = s;
  if (d == 0){
    float sb = 0.f;
    for (int k = 0; k < 512; ++k) sb += out_b[k] * fc2_w[k * 5 + j];
    bf[j] = sb + fc2_b[j];
  }
}

// ---------------- kv_w transpose -> bf16 Bt[1024][512] ----------------
__global__ __launch_bounds__(256) void wtr_kernel(const float* __restrict__ kvw,
                                                  unsigned short* __restrict__ Bt){
  long id = (long)blockIdx.x * 256 + threadIdx.x;   // 524288 total
  int n = (int)(id >> 9), k = (int)(id & 511);
  Bt[id] = (unsigned short)f2bf(kvw[(long)k * NKV + n]);
}

// ---------------- sk_w transpose (f32): skwT[j][e] = sk_w[e][j] ----------------
__global__ __launch_bounds__(256) void skwt_kernel(const float* __restrict__ skw,
                                                   float* __restrict__ skwT){
  long id = (long)blockIdx.x * 256 + threadIdx.x;   // 262144
  int e = (int)(id >> 9), j = (int)(id & 511);
  skwT[(long)j * 512 + e] = skw[id];
}

// ---------------- prep: (mem+pos) -> bf16 A[MPAD][512], pad rows zero ----------------
__global__ __launch_bounds__(256) void prep_kernel(const float* __restrict__ mem,
                                                   const float* __restrict__ pos,
                                                   unsigned short* __restrict__ Abf){
  long idx = (long)blockIdx.x * 256 + threadIdx.x;  // MPAD*512/4 = 2,572,288
  int r = (int)(idx >> 7);
  int cv = (int)(idx & 127) << 2;
  ushort4 o;
  if (r < NMEM){
    float4 m4 = *(const float4*)(mem + (long)r * 512 + cv);
    float4 p4 = *(const float4*)(pos + (r & 31) * 512 + cv);
    o.x = (unsigned short)f2bf(m4.x + p4.x);
    o.y = (unsigned short)f2bf(m4.y + p4.y);
    o.z = (unsigned short)f2bf(m4.z + p4.z);
    o.w = (unsigned short)f2bf(m4.w + p4.w);
  } else {
    o.x = o.y = o.z = o.w = 0;
  }
  *(ushort4*)(Abf + idx * 4) = o;
}

// ---------------- chunk summarize ----------------
__global__ __launch_bounds__(512) void sum_kernel(const float* __restrict__ memories,
                                                  const void* __restrict__ mask,
                                                  const int* __restrict__ flagp,
                                                  float* __restrict__ summ,
                                                  float* __restrict__ chunkden){
  int blk = blockIdx.x;              // 0..2499 = b*625+n
  int b = blk / NCHUNK, n = blk % NCHUNK;
  int t = threadIdx.x;
  int flag = *flagp;
  long mbase = (long)b * NMEM + (long)n * CHUNK;
  float den = 0.f;
  for (int c = 0; c < CHUNK; ++c) den += mask_at(mask, flag, mbase + c) ? 1.f : 0.f;
  const float* rowb = memories + mbase * HID;
  float s = 0.f;
  for (int c = 0; c < CHUNK; ++c){
    if (mask_at(mask, flag, mbase + c)) s += rowb[(long)c * HID + t];
  }
  summ[(long)blk * HID + t] = s / (den + 1e-5f);
  if (t == 0) chunkden[blk] = den;
}

// ---------------- vker: v1 -> W2buf col 512 (+zero pad cols), v2, gamma ----------------
__global__ __launch_bounds__(512) void vker(const float* __restrict__ sq_w,
                                            const float* __restrict__ sq_b,
                                            const float* __restrict__ sk_w,
                                            const float* __restrict__ sk_b,
                                            float* __restrict__ W2buf,
                                            float* __restrict__ v2,
                                            float* __restrict__ gbuf){
  int t = threadIdx.x;
  if (blockIdx.x == 0){
    // v1[d] = sum_j sq_w[d][j]*sk_b[j]
    float s = 0.f;
    for (int j = 0; j < 512; ++j) s += sq_w[(long)t * 512 + j] * sk_b[j];
    W2buf[(long)t * W2LD + 512] = s;
    for (int c = 513; c < W2LD; ++c) W2buf[(long)t * W2LD + c] = 0.f;
  } else if (blockIdx.x == 1){
    // v2[e] = sum_j sk_w[e][j]*sq_b[j]
    float s = 0.f;
    for (int j = 0; j < 512; ++j) s += sk_w[(long)t * 512 + j] * sq_b[j];
    v2[t] = s;
  } else {
    if (t == 0){
      float s = 0.f;
      for (int j = 0; j < 512; ++j) s += sq_b[j] * sk_b[j];
      gbuf[0] = s;
    }
  }
}

// ---------------- generic f32 NN GEMM: C = A[M][K] @ B[K][N] * scale ----------------
// grid (M/16, N/64), block 256. Wave w: rows r0..r0+3; lane: one column.
// A loads wave-uniform (L1 broadcast); B loads coalesced. No LDS, no barriers.
__global__ __launch_bounds__(256) void gemm_nn(const float* __restrict__ A, int lda,
                                               const float* __restrict__ B, int ldb,
                                               float* __restrict__ C, int ldc,
                                               int K, float scale){
  int tid = threadIdx.x;
  int lane = tid & 63, w = tid >> 6;
  int r0 = blockIdx.x * 16 + w * 4;
  int n  = blockIdx.y * 64 + lane;
  const float* a0 = A + (long)r0 * lda;
  const float* bp = B + n;
  float acc0 = 0.f, acc1 = 0.f, acc2 = 0.f, acc3 = 0.f;
#pragma unroll 2
  for (int k = 0; k < K; k += 4){
    float b0 = bp[(long)k * ldb];
    float b1 = bp[(long)(k + 1) * ldb];
    float b2 = bp[(long)(k + 2) * ldb];
    float b3 = bp[(long)(k + 3) * ldb];
    float4 a;
    a = *(const float4*)(a0 + k);
    acc0 += a.x * b0 + a.y * b1 + a.z * b2 + a.w * b3;
    a = *(const float4*)(a0 + lda + k);
    acc1 += a.x * b0 + a.y * b1 + a.z * b2 + a.w * b3;
    a = *(const float4*)(a0 + 2 * lda + k);
    acc2 += a.x * b0 + a.y * b1 + a.z * b2 + a.w * b3;
    a = *(const float4*)(a0 + 3 * lda + k);
    acc3 += a.x * b0 + a.y * b1 + a.z * b2 + a.w * b3;
  }
  C[(long)r0 * ldc + n]       = acc0 * scale;
  C[(long)(r0 + 1) * ldc + n] = acc1 * scale;
  C[(long)(r0 + 2) * ldc + n] = acc2 * scale;
  C[(long)(r0 + 3) * ldc + n] = acc3 * scale;
}

// ---------------- summT: summText[b][e][n] (transpose + ones row + zero pad) ----------------
__global__ __launch_bounds__(256) void summt_kernel(const float* __restrict__ summ,
                                                    float* __restrict__ summText){
  long id = (long)blockIdx.x * 256 + threadIdx.x;   // 4*520*640 = 1,331,200
  int b = (int)(id / (STROWS * LGLD));
  int rem = (int)(id - (long)b * STROWS * LGLD);
  int e = rem / LGLD, n = rem % LGLD;
  float v;
  if (e < 512)      v = (n < NCHUNK) ? summ[((long)b * NCHUNK + n) * 512 + e] : 0.f;
  else if (e == 512) v = 1.f;
  else               v = 0.f;
  summText[id] = v;
}

// ---------------- beta: betag[b*640+n] = summ_row . v2 + gamma ----------------
__global__ __launch_bounds__(256) void beta_kernel(const float* __restrict__ summ,
                                                   const float* __restrict__ v2,
                                                   const float* __restrict__ gbuf,
                                                   float* __restrict__ betag){
  int w = threadIdx.x >> 6, lane = threadIdx.x & 63;
  int row = blockIdx.x * 4 + w;          // 0..2499
  const float* r = summ + (long)row * 512;
  float s = 0.f;
#pragma unroll
  for (int c = 0; c < 8; ++c) s += r[lane + 64 * c] * v2[lane + 64 * c];
  for (int d = 32; d >= 1; d >>= 1) s += __shfl_xor(s, d, 64);
  if (lane == 0){
    int b = row / NCHUNK, n = row % NCHUNK;
    betag[b * LGLD + n] = s + gbuf[0];
  }
}

// ---------------- logits (NN form): per batch u_ext[128][520] @ summText[520][640] ----------------
__global__ __launch_bounds__(256) void logits_nn(const float* __restrict__ u_ext,
                                                 const float* __restrict__ summText,
                                                 const float* __restrict__ betag,
                                                 const float* __restrict__ chunkden,
                                                 float* __restrict__ logits){
  int b = blockIdx.z;
  int tid = threadIdx.x;
  int lane = tid & 63, w = tid >> 6;
  int r0 = blockIdx.x * 16 + w * 4;      // i
  int n  = blockIdx.y * 64 + lane;
  const float* a0 = u_ext + ((long)b * QN + r0) * W2LD;
  const float* bp = summText + (long)b * STROWS * LGLD + n;
  float acc0 = 0.f, acc1 = 0.f, acc2 = 0.f, acc3 = 0.f;
#pragma unroll 2
  for (int k = 0; k < STROWS; k += 4){
    float b0 = bp[(long)k * LGLD];
    float b1 = bp[(long)(k + 1) * LGLD];
    float b2 = bp[(long)(k + 2) * LGLD];
    float b3 = bp[(long)(k + 3) * LGLD];
    float4 a;
    a = *(const float4*)(a0 + k);
    acc0 += a.x * b0 + a.y * b1 + a.z * b2 + a.w * b3;
    a = *(const float4*)(a0 + W2LD + k);
    acc1 += a.x * b0 + a.y * b1 + a.z * b2 + a.w * b3;
    a = *(const float4*)(a0 + 2 * W2LD + k);
    acc2 += a.x * b0 + a.y * b1 + a.z * b2 + a.w * b3;
    a = *(const float4*)(a0 + 3 * W2LD + k);
    acc3 += a.x * b0 + a.y * b1 + a.z * b2 + a.w * b3;
  }
  if (n < NCHUNK){
    float bet = betag[b * LGLD + n];
    bool dead = (chunkden[b * NCHUNK + n] <= 0.f);
    float v0 = (acc0 + bet) * LOGIT_SCALE;
    float v1 = (acc1 + bet) * LOGIT_SCALE;
    float v2 = (acc2 + bet) * LOGIT_SCALE;
    float v3 = (acc3 + bet) * LOGIT_SCALE;
    if (dead){ v0 = v1 = v2 = v3 = -FLT_MAX; }
    long base = ((long)b * QN + r0) * LGLD + n;
    logits[base]            = v0;
    logits[base + LGLD]     = v1;
    logits[base + 2 * LGLD] = v2;
    logits[base + 3 * LGLD] = v3;
  }
}

// ---------------- top-8 + softmax weights, one wave per (b,i) row ----------------
__global__ __launch_bounds__(64) void topk_kernel(const float* __restrict__ logits,
                                                  int* __restrict__ topi_out,
                                                  float* __restrict__ wts_out){
  int row = blockIdx.x;   // b*128+i
  __shared__ float lds[NCHUNK];
  __shared__ float topv[TOPKK];
  __shared__ int   topi[TOPKK];
  int lane = threadIdx.x;
  for (int idx = lane; idx < NCHUNK; idx += 64) lds[idx] = logits[(long)row * LGLD + idx];
  __syncthreads();
  for (int it = 0; it < TOPKK; ++it){
    float bv = -INFINITY; int bi = 0x7fffffff;
    for (int idx = lane; idx < NCHUNK; idx += 64){
      float v = lds[idx];
      if (v > bv){ bv = v; bi = idx; }
    }
    for (int d = 32; d >= 1; d >>= 1){
      float ov = __shfl_xor(bv, d, 64);
      int   oi = __shfl_xor(bi, d, 64);
      if (ov > bv || (ov == bv && oi < bi)){ bv = ov; bi = oi; }
    }
    if (lane == 0){ topv[it] = bv; topi[it] = bi; lds[bi] = -INFINITY; }
    __syncthreads();
  }
  if (lane == 0){
    float m = topv[0];
    for (int r = 1; r < TOPKK; ++r) m = fmaxf(m, topv[r]);
    float e[TOPKK], s = 0.f;
    for (int r = 0; r < TOPKK; ++r){ e[r] = expf(topv[r] - m); s += e[r]; }
    for (int r = 0; r < TOPKK; ++r){
      wts_out[(long)row * TOPKK + r] = e[r] / s;
      topi_out[(long)row * TOPKK + r] = topi[r];
    }
  }
}

// ---------------- KV GEMM (m97 structure): A[MPAD][512]bf16 @ Bt[1024][512]bf16^T -> kv bf16 ----------------
__global__ __launch_bounds__(256) void kv_gemm(const unsigned short* __restrict__ A,
                                               const unsigned short* __restrict__ Bt,
                                               unsigned short* __restrict__ kvout){
  __shared__ unsigned short As[128 * 32];   // 8 KB
  __shared__ unsigned short Bs[128 * 32];   // 8 KB
  int id = blockIdx.x;
  int panel = id >> 3, nb = id & 7;
  int m0 = panel << 7, n0 = nb << 7;
  int tid = threadIdx.x;
  int wid = tid >> 6, lane = tid & 63;
  int wr = wid >> 1, wc = wid & 1;
  int lr = lane & 15, lg = lane >> 4;

  int srow = wid * 16 + (lane >> 2);
  int scol = (lane & 3) << 3;
  const unsigned short* gA0 = A  + (long)(m0 + srow) * 512 + scol;
  const unsigned short* gA1 = gA0 + 64 * 512;
  const unsigned short* gB0 = Bt + (long)(n0 + srow) * 512 + scol;
  const unsigned short* gB1 = gB0 + 64 * 512;
  unsigned short* lA0 = &As[(wid * 16) * 32];
  unsigned short* lA1 = &As[(64 + wid * 16) * 32];
  unsigned short* lB0 = &Bs[(wid * 16) * 32];
  unsigned short* lB1 = &Bs[(64 + wid * 16) * 32];

  f32x4 acc[4][4];
#pragma unroll
  for (int i = 0; i < 4; ++i)
#pragma unroll
    for (int j = 0; j < 4; ++j) acc[i][j] = (f32x4)0.f;

  for (int k0 = 0; k0 < 512; k0 += 32){
    gload16(gA0 + k0, lA0);
    gload16(gA1 + k0, lA1);
    gload16(gB0 + k0, lB0);
    gload16(gB1 + k0, lB1);
    __syncthreads();
    bf16x8 af[4], bfv[4];
#pragma unroll
    for (int mi = 0; mi < 4; ++mi) af[mi]  = *(const bf16x8*)&As[(wr * 64 + mi * 16 + lr) * 32 + lg * 8];
#pragma unroll
    for (int ni = 0; ni < 4; ++ni) bfv[ni] = *(const bf16x8*)&Bs[(wc * 64 + ni * 16 + lr) * 32 + lg * 8];
#pragma unroll
    for (int mi = 0; mi < 4; ++mi)
#pragma unroll
      for (int ni = 0; ni < 4; ++ni)
        acc[mi][ni] = __builtin_amdgcn_mfma_f32_16x16x32_bf16(af[mi], bfv[ni], acc[mi][ni], 0, 0, 0);
    __syncthreads();
  }
#pragma unroll
  for (int mi = 0; mi < 4; ++mi)
#pragma unroll
    for (int ni = 0; ni < 4; ++ni)
#pragma unroll
      for (int rr = 0; rr < 4; ++rr){
        int gr = m0 + wr * 64 + mi * 16 + lg * 4 + rr;
        int gn = n0 + wc * 64 + ni * 16 + lr;
        kvout[(long)gr * NKV + gn] = (unsigned short)f2bf(acc[mi][ni][rr]);
      }
}

// ---------------- attention per (i, k-slot) for one batch ----------------
__global__ __launch_bounds__(256) void attn_kernel(const float* __restrict__ qh,
                                                   const unsigned short* __restrict__ kv,
                                                   const int* __restrict__ topidx,
                                                   const float* __restrict__ wts,
                                                   const void* __restrict__ mask,
                                                   const int* __restrict__ flagp,
                                                   float* __restrict__ osc,
                                                   int bb){
  int bx = blockIdx.x;
  int i = bx >> 3, k = bx & 7;
  int t = threadIdx.x;
  __shared__ float qs[HID];
  __shared__ float att[HEADS][CHUNK + 1];
  long sel = ((long)(bb * QN + i)) * TOPKK + k;
  int chunk = topidx[sel];
  float w8 = wts[sel];
  const float* qrow = qh + ((long)(bb * QN + i)) * HID;
  qs[t] = qrow[t]; qs[t + 256] = qrow[t + 256];
  __syncthreads();
  int flag = *flagp;
  int h = t >> 5, c = t & 31;
  const unsigned short* krow = kv + ((long)(chunk * CHUNK + c)) * NKV + h * DHEAD;
  float s = 0.f;
#pragma unroll
  for (int e8 = 0; e8 < 8; ++e8){
    bf16x8 k8 = *(const bf16x8*)(krow + e8 * 8);
#pragma unroll
    for (int j = 0; j < 8; ++j) s += qs[h * DHEAD + e8 * 8 + j] * bf2f((unsigned short)k8[j]);
  }
  bool mv = mask_at(mask, flag, (long)bb * NMEM + (long)chunk * CHUNK + c);
  if (!mv) s = -FLT_MAX;
  float m = s;
  for (int d = 16; d >= 1; d >>= 1) m = fmaxf(m, __shfl_xor(m, d, 32));
  float p = expf(s - m);
  float su = p;
  for (int d = 16; d >= 1; d >>= 1) su += __shfl_xor(su, d, 32);
  att[h][c] = p / su;
  __syncthreads();
  int e0 = (t & 31) * 2;
  float o0 = 0.f, o1 = 0.f;
#pragma unroll 4
  for (int c2 = 0; c2 < CHUNK; ++c2){
    float a = att[h][c2];
    const unsigned short* vr = kv + ((long)(chunk * CHUNK + c2)) * NKV + 512 + h * DHEAD + e0;
    o0 += a * bf2f(vr[0]);
    o1 += a * bf2f(vr[1]);
  }
  long ob = (((long)(bb * QN + i) * TOPKK) + k) * HID + h * DHEAD + e0;
  osc[ob]     = o0 * w8;
  osc[ob + 1] = o1 * w8;
}

// ---------------- final: reduce over k, then @ (out_w@fc2_w) + folded bias ----------------
__global__ __launch_bounds__(512) void final_kernel(const float* __restrict__ osc,
                                                    const float* __restrict__ Wf,
                                                    const float* __restrict__ bfold,
                                                    float* __restrict__ out){
  int bi = blockIdx.x;   // b*128+i
  int t = threadIdx.x;
  __shared__ float lds[HID];
  float s = 0.f;
  for (int k = 0; k < TOPKK; ++k) s += osc[(((long)bi * TOPKK) + k) * HID + t];
  lds[t] = s;
  __syncthreads();
  if (t < 5){
    float a = bfold[t];
    for (int d = 0; d < HID; ++d) a += lds[d] * Wf[d * 5 + t];
    out[bi * 5 + t] = a;
  }
}

extern "C" void kernel_launch(void* const* d_in, const int* in_sizes, int n_in,
                              void* d_out, int out_size, void* d_ws, size_t ws_size,
                              hipStream_t stream) {
  const float* queries  = (const float*)d_in[1];
  const float* memories = (const float*)d_in[2];
  const void*  mask     = d_in[3];
  const float* sq_w = (const float*)d_in[10];
  const float* sq_b = (const float*)d_in[11];
  const float* sk_w = (const float*)d_in[12];
  const float* sk_b = (const float*)d_in[13];
  const float* q_w  = (const float*)d_in[14];
  const float* kv_w = (const float*)d_in[15];
  const float* out_w = (const float*)d_in[16];
  const float* out_b = (const float*)d_in[17];
  const float* fc2_w = (const float*)d_in[18];
  const float* fc2_b = (const float*)d_in[19];
  float* out = (float*)d_out;

  char* ws = (char*)d_ws;
  size_t o_sum  = 0;                        // 5,120,000
  size_t o_den  = o_sum + 5120000;          // 10,240
  size_t o_pos  = o_den + 10240;            // 65,536
  size_t o_wf   = o_pos + 65536;            // 10,240
  size_t o_bf   = o_wf  + 10240;            // 512
  size_t o_ti   = o_bf  + 512;              // 16,384
  size_t o_wt   = o_ti  + 16384;            // 16,384
  size_t o_flag = o_wt  + 16384;            // 512
  size_t o_qh   = o_flag + 512;             // 1,048,576
  size_t o_w2   = o_qh  + 1048576;          // 1,179,648 (512 x 576 f32)
  size_t o_uex  = o_w2  + 1179648;          // 1,179,648
  size_t o_st   = o_uex + 1179648;          // 5,324,800 (4 x 520 x 640 f32)
  size_t o_bg   = o_st  + 5324800;          // 10,240
  size_t o_v2   = o_bg  + 10240;            // 2,048
  size_t o_gm   = o_v2  + 2048;             // 512
  size_t o_lg   = o_gm  + 512;              // 1,310,720 (512 x 640 f32)
  size_t o_osc  = o_lg  + 1310720;          // 8,388,608
  size_t o_skt  = o_osc + 8388608;          // 1,048,576
  size_t o_abf  = o_skt + 1048576;          // 20,578,304
  size_t o_btw  = o_abf + 20578304;         // 1,048,576
  size_t o_kv   = o_btw + 1048576;          // 41,156,608

  float* summ  = (float*)(ws + o_sum);
  float* den   = (float*)(ws + o_den);
  float* pos   = (float*)(ws + o_pos);
  float* Wf    = (float*)(ws + o_wf);
  float* bfold = (float*)(ws + o_bf);
  int*   ti    = (int*)  (ws + o_ti);
  float* wt    = (float*)(ws + o_wt);
  int*   flagp = (int*)  (ws + o_flag);
  float* qh    = (float*)(ws + o_qh);
  float* W2buf = (float*)(ws + o_w2);
  float* u_ext = (float*)(ws + o_uex);
  float* summText = (float*)(ws + o_st);
  float* betag = (float*)(ws + o_bg);
  float* v2    = (float*)(ws + o_v2);
  float* gbuf  = (float*)(ws + o_gm);
  float* logit = (float*)(ws + o_lg);
  float* osc   = (float*)(ws + o_osc);
  float* skwT  = (float*)(ws + o_skt);
  unsigned short* abf   = (unsigned short*)(ws + o_abf);
  unsigned short* btw   = (unsigned short*)(ws + o_btw);
  unsigned short* kvbuf = (unsigned short*)(ws + o_kv);

  misc_kernel<<<dim3(32), dim3(512), 0, stream>>>(pos, flagp, mask);
  fold_kernel<<<dim3(5), dim3(512), 0, stream>>>(out_w, out_b, fc2_w, fc2_b, Wf, bfold);
  wtr_kernel<<<dim3(2048), dim3(256), 0, stream>>>(kv_w, btw);
  skwt_kernel<<<dim3(1024), dim3(256), 0, stream>>>(sk_w, skwT);
  sum_kernel<<<dim3(NB * NCHUNK), dim3(512), 0, stream>>>(memories, mask, flagp, summ, den);
  vker<<<dim3(3), dim3(512), 0, stream>>>(sq_w, sq_b, sk_w, sk_b, W2buf, v2, gbuf);

  // W2 = sq_w @ sk_w^T  (written into W2buf cols 0..511; col 512 = v1 from vker)
  gemm_nn<<<dim3(32, 8), dim3(256), 0, stream>>>(sq_w, 512, skwT, 512, W2buf, W2LD, 512, 1.0f);
  // u_ext = queries @ W2buf  (cols 0..511 = u, col 512 = alpha, 513.. = 0)
  gemm_nn<<<dim3(32, 9), dim3(256), 0, stream>>>(queries, 512, W2buf, W2LD, u_ext, W2LD, 512, 1.0f);
  // qh = queries @ q_w * 0.125
  gemm_nn<<<dim3(32, 8), dim3(256), 0, stream>>>(queries, 512, q_w, 512, qh, 512, 512, 0.125f);

  summt_kernel<<<dim3(5200), dim3(256), 0, stream>>>(summ, summText);
  beta_kernel<<<dim3(625), dim3(256), 0, stream>>>(summ, v2, gbuf, betag);
  logits_nn<<<dim3(8, 10, NB), dim3(256), 0, stream>>>(u_ext, summText, betag, den, logit);
  topk_kernel<<<dim3(NB * QN), dim3(64), 0, stream>>>(logit, ti, wt);

  for (int bb = 0; bb < NB; ++bb){
    const float* memb = memories + (long)bb * NMEM * HID;
    prep_kernel<<<dim3(10048), dim3(256), 0, stream>>>(memb, pos, abf);
    kv_gemm<<<dim3(157 * 8), dim3(256), 0, stream>>>(abf, btw, kvbuf);
    attn_kernel<<<dim3(QN * TOPKK), dim3(256), 0, stream>>>(qh, kvbuf, ti, wt, mask, flagp, osc, bb);
  }
  final_kernel<<<dim3(NB * QN), dim3(512), 0, stream>>>(osc, Wf, bfold, out);
}